// Round 5
// baseline (392.875 us; speedup 1.0000x reference)
//
#include <hip/hip_runtime.h>
#include <hip/hip_bf16.h>

#define M_TOKENS 4096
#define K_IN     4096
#define N_OUT    11008

#define BM 256
#define BN 256
#define BK 64
#define KTILES (K_IN / BK)   // 64

typedef __bf16 bf16x8 __attribute__((ext_vector_type(8)));
typedef float  f32x4  __attribute__((ext_vector_type(4)));

__device__ __forceinline__ void async_copy16(const void* g, void* l) {
    __builtin_amdgcn_global_load_lds(
        (const __attribute__((address_space(1))) void*)g,
        (__attribute__((address_space(3))) void*)l, 16, 0, 0);
}

// ---- x fp32 -> bf16 cast, 8 elems/thread ----
__global__ __launch_bounds__(256) void cast_x_kernel(const float* __restrict__ x,
                                                     __hip_bfloat16* __restrict__ xb) {
    size_t idx = (size_t)blockIdx.x * 256 + threadIdx.x;
    const float4* xf = reinterpret_cast<const float4*>(x) + idx * 2;
    float4 a = xf[0], b = xf[1];
    float v[8] = {a.x, a.y, a.z, a.w, b.x, b.y, b.z, b.w};
    alignas(16) __hip_bfloat16 t[8];
#pragma unroll
    for (int j = 0; j < 8; ++j) t[j] = __float2bfloat16(v[j]);
    *reinterpret_cast<uint4*>(xb + idx * 8) = *reinterpret_cast<const uint4*>(t);
}

// ---- int4-code dequant: wq[n,k] int32 -> wb[n,k] bf16 (B^T layout), 8 k/thread ----
__global__ __launch_bounds__(256) void dequant_kernel(const int* __restrict__ wq,
                                                      const float* __restrict__ snz,
                                                      __hip_bfloat16* __restrict__ wb) {
    size_t idx = (size_t)blockIdx.x * 256 + threadIdx.x;   // n*(K/8) + k8
    int n  = (int)(idx >> 9);         // K_IN/8 = 512
    int k8 = (int)(idx & 511);
    int g  = k8 >> 4;                 // (k8*8)/128
    const float* sz = snz + ((size_t)g * N_OUT + n) * 2;
    float scale = sz[0], zero = sz[1];
    const int4* q4 = reinterpret_cast<const int4*>(wq + (size_t)n * K_IN + (size_t)k8 * 8);
    int4 qa = q4[0], qb = q4[1];
    int q[8] = {qa.x, qa.y, qa.z, qa.w, qb.x, qb.y, qb.z, qb.w};
    alignas(16) __hip_bfloat16 t[8];
#pragma unroll
    for (int j = 0; j < 8; ++j)
        t[j] = __float2bfloat16((float)(q[j] - 8) * scale + zero);
    *reinterpret_cast<uint4*>(wb + idx * 8) = *reinterpret_cast<const uint4*>(t);
}

// ================= 256x256 bf16 GEMM, 1-barrier-per-K-tile schedule ==========
// C[M,N] = Xb[M,K] @ Wb[N,K]^T, fp32 out. 8 waves (2M x 4N), BK=64.
// Round-4 lesson: per-phase barriers SERIALIZE the LDS pipe (576 cyc/phase of
// ds_read service) against the MFMA pipe (621 cyc/phase) -> measured 1240
// cyc/phase. Fix: reads in tile t touch only buffers staged in tile t-1;
// staging in tile t writes only tile t+1's buffers (disjoint). So ONE sync
// per K-tile suffices: s_waitcnt vmcnt(0) lgkmcnt(0) BEFORE s_barrier (per-wave
// drain, wait-then-barrier invariant from round 3). Inside the tile, waves
// drift: one wave's ds_reads overlap the other SIMD-wave's MFMAs.

#define SCB()  __builtin_amdgcn_sched_barrier(0)
#define BOUNDARY() { SCB(); \
    asm volatile("s_waitcnt vmcnt(0) lgkmcnt(0)" ::: "memory"); \
    __builtin_amdgcn_s_barrier(); SCB(); }

#define RD_AL(T, KK) \
    _Pragma("unroll") for (int mi = 0; mi < 4; ++mi) aL[mi] = readA(T, mi, KK);
#define RD_AH(T, KK) \
    _Pragma("unroll") for (int mi = 0; mi < 4; ++mi) aH[mi] = readA(T, 4 + mi, KK);
#define RD_B4(T, KK) \
    _Pragma("unroll") for (int ni = 0; ni < 4; ++ni) bk[ni] = readB(T, ni, KK);

#define MFMA16(AOFF, FRAG) \
    __builtin_amdgcn_s_setprio(1); \
    { \
        _Pragma("unroll") for (int mi = 0; mi < 4; ++mi) \
        _Pragma("unroll") for (int ni = 0; ni < 4; ++ni) \
            acc[AOFF + mi][ni] = __builtin_amdgcn_mfma_f32_16x16x32_bf16( \
                FRAG[mi], bk[ni], acc[AOFF + mi][ni], 0, 0, 0); \
    } \
    __builtin_amdgcn_s_setprio(0);

// One K-tile: consume (CA,CB) staged last tile; stage (NA,NB) <- K-tile KN.
#define TILE(CA, CB, NA, NB, KN) \
    BOUNDARY(); \
    RD_AL(CA, 0); RD_B4(CB, 0); \
    stageA(NA, KN); stageB(NB, KN); \
    MFMA16(0, aL); \
    RD_AH(CA, 0); \
    MFMA16(4, aH); \
    RD_AL(CA, 1); RD_B4(CB, 1); \
    MFMA16(0, aL); \
    RD_AH(CA, 1); \
    MFMA16(4, aH);

__global__ __launch_bounds__(512, 2) void gemm8p_kernel(
        const __hip_bfloat16* __restrict__ Xb,
        const __hip_bfloat16* __restrict__ Wb,
        float* __restrict__ C) {
    __shared__ alignas(16) char smem[131072];
    char* const ldsA = smem;            // [2][256 rows][64 bf16 = 128B]
    char* const ldsB = smem + 65536;

    const int tid  = threadIdx.x;
    const int lane = tid & 63;
    const int wave = tid >> 6;
    const int wr   = wave >> 2;     // 0..1  (M half)
    const int wc   = wave & 3;      // 0..3  (N quarter)
    const int l15  = lane & 15;
    const int lrow = lane >> 3;     // staging row-in-chunk
    const int ssw  = (((lane & 7) ^ lrow) << 4);   // pre-swizzled source col (bytes)

    // XCD-bijective swizzle (grid = 688, 688 % 8 == 0)
    unsigned bid = blockIdx.x;
    unsigned per = gridDim.x >> 3;               // 86
    unsigned swz = (bid & 7u) * per + (bid >> 3);
    const int tn = (int)(swz % (N_OUT / BN));    // 43
    const int tm = (int)(swz / (N_OUT / BN));    // 16
    const int m0 = tm * BM;
    const int n0 = tn * BN;

    // swizzled read column (bytes within a 128B row); kk toggles bit 6
    const int colswz = (((lane >> 4) << 4) ^ ((lane & 7) << 4));

    f32x4 acc[8][4];
#pragma unroll
    for (int i = 0; i < 8; ++i)
#pragma unroll
        for (int j = 0; j < 4; ++j) {
            f32x4 z = {0.f, 0.f, 0.f, 0.f};
            acc[i][j] = z;
        }
    bf16x8 aL[4], aH[4], bk[4];

    // stage a full 32KB tile (4 x global_load_lds/thread, 8 rows per chunk)
    auto stageA = [&](char* dstTile, int kt) {
#pragma unroll
        for (int j = 0; j < 4; ++j) {
            int rb = (wave * 4 + j) * 8;
            const char* g = (const char*)Xb + ((size_t)(m0 + rb + lrow) * K_IN) * 2
                            + (size_t)kt * 128 + ssw;
            async_copy16(g, dstTile + rb * 128);
        }
    };
    auto stageB = [&](char* dstTile, int kt) {
#pragma unroll
        for (int j = 0; j < 4; ++j) {
            int rb = (wave * 4 + j) * 8;
            const char* g = (const char*)Wb + ((size_t)(n0 + rb + lrow) * K_IN) * 2
                            + (size_t)kt * 128 + ssw;
            async_copy16(g, dstTile + rb * 128);
        }
    };
    auto readA = [&](char* tile, int mi8, int kk) -> bf16x8 {
        return *(const bf16x8*)(tile + (wr * 128 + mi8 * 16 + l15) * 128 + (colswz ^ (kk << 6)));
    };
    auto readB = [&](char* tile, int ni4, int kk) -> bf16x8 {
        return *(const bf16x8*)(tile + (wc * 64 + ni4 * 16 + l15) * 128 + (colswz ^ (kk << 6)));
    };

    char* const A0 = ldsA;   char* const A1 = ldsA + 32768;
    char* const B0 = ldsB;   char* const B1 = ldsB + 32768;

    // ---- prologue: stage tile 0 into buf0 (8 loads); TILE's BOUNDARY drains it ----
    stageA(A0, 0); stageB(B0, 0);

    for (int i = 0; i < KTILES / 2; ++i) {
        const int k1 = (2 * i + 1) & (KTILES - 1);
        const int k2 = (2 * i + 2) & (KTILES - 1);   // wraps on last iter: harmless dead stage
        TILE(A0, B0, A1, B1, k1)   // consume buf0, stage k1 -> buf1
        TILE(A1, B1, A0, B0, k2)   // consume buf1, stage k2 -> buf0
    }

    // ---- epilogue: D layout col=lane&15, row=(lane>>4)*4+e ----
    const int r4 = (lane >> 4) << 2;
#pragma unroll
    for (int mi = 0; mi < 8; ++mi)
#pragma unroll
        for (int ni = 0; ni < 4; ++ni)
#pragma unroll
            for (int e = 0; e < 4; ++e) {
                int row = m0 + wr * 128 + mi * 16 + r4 + e;
                int col = n0 + wc * 64 + ni * 16 + l15;
                C[(size_t)row * N_OUT + col] = acc[mi][ni][e];
            }
}

extern "C" void kernel_launch(void* const* d_in, const int* in_sizes, int n_in,
                              void* d_out, int out_size, void* d_ws, size_t ws_size,
                              hipStream_t stream) {
    const float* x   = (const float*)d_in[0];
    const int*   wq  = (const int*)d_in[1];
    const float* snz = (const float*)d_in[2];
    float* out = (float*)d_out;

    __hip_bfloat16* Xb = (__hip_bfloat16*)d_ws;                                        // 32 MB
    __hip_bfloat16* Wb = (__hip_bfloat16*)((char*)d_ws + (size_t)M_TOKENS * K_IN * 2); // 86 MB

    cast_x_kernel<<<(M_TOKENS * (size_t)K_IN) / 8 / 256, 256, 0, stream>>>(x, Xb);
    dequant_kernel<<<((size_t)N_OUT * K_IN) / 8 / 256, 256, 0, stream>>>(wq, snz, Wb);
    gemm8p_kernel<<<(M_TOKENS / BM) * (N_OUT / BN), 512, 0, stream>>>(Xb, Wb, out);
}